// Round 6
// baseline (76.458 us; speedup 1.0000x reference)
//
#include <hip/hip_runtime.h>
#include <hip/hip_bf16.h>

#define N_NODES 100000
#define N_EDGES 1600000
#define IN_F 256
#define OUT_F 64

typedef short bf16x8 __attribute__((ext_vector_type(8)));
typedef float f32x4 __attribute__((ext_vector_type(4)));
typedef unsigned short u16x8 __attribute__((ext_vector_type(8)));

__device__ __forceinline__ short f2bf(float f) {
  unsigned u = __float_as_uint(f);
  u += 0x7FFF + ((u >> 16) & 1);  // round-to-nearest-even
  return (short)(u >> 16);
}
__device__ __forceinline__ float bf2f(unsigned short u) {
  return __uint_as_float(((unsigned)u) << 16);
}

// ---------------------------------------------------------------------------
// Kernel 1: CSR row pointers from sorted row_idx (binary search).
// ---------------------------------------------------------------------------
__global__ __launch_bounds__(256) void build_row_ptr_kernel(
    const int* __restrict__ row_idx, int* __restrict__ row_ptr) {
  int i = blockIdx.x * blockDim.x + threadIdx.x;
  if (i > N_NODES) return;
  int lo = 0, hi = N_EDGES;
  while (lo < hi) {
    int mid = (lo + hi) >> 1;
    if (row_idx[mid] < i) lo = mid + 1; else hi = mid;
  }
  row_ptr[i] = lo;
}

// ---------------------------------------------------------------------------
// Kernel 1b: precompute W as bf16 MFMA B-fragments, fragment-major.
//   k = s*32 + (l>>4)*8 + j, col = t*16 + (l&15)
// ---------------------------------------------------------------------------
__global__ __launch_bounds__(256) void wfrag_kernel(
    const float* __restrict__ W, short* __restrict__ Wf) {
  int tid = blockIdx.x * blockDim.x + threadIdx.x;  // [0, 2048)
  if (tid >= 2048) return;
  int s = tid >> 8;
  int r = tid & 255;
  int t = r >> 6;
  int lane = r & 63;
  int col = t * 16 + (lane & 15);
  int kbase = s * 32 + ((lane >> 4) & 3) * 8;
#pragma unroll
  for (int j = 0; j < 8; ++j) {
    Wf[(size_t)tid * 8 + j] = f2bf(W[(size_t)(kbase + j) * OUT_F + col]);
  }
}

// ---------------------------------------------------------------------------
// Kernel 2: support(bf16) = x @ W via bf16 MFMA (16x16x32).
// C/D layout (HW-verified): col = lane&15, row = (lane>>4)*4 + reg.
// ---------------------------------------------------------------------------
__global__ __launch_bounds__(256) void gemm_kernel(
    const float* __restrict__ x, const short* __restrict__ Wf,
    unsigned short* __restrict__ supB) {
  __shared__ short sWf[8 * 4 * 64 * 8];  // 32 KB
  {
    const float4* g = reinterpret_cast<const float4*>(Wf);
    float4* s4 = reinterpret_cast<float4*>(sWf);
#pragma unroll
    for (int i = 0; i < 8; ++i) s4[threadIdx.x + i * 256] = g[threadIdx.x + i * 256];
  }
  __syncthreads();

  const int lane = threadIdx.x & 63;
  const int wave = threadIdx.x >> 6;
  const int r0_base = blockIdx.x * 64 + wave * 16;

  int arow = r0_base + (lane & 15);
  if (arow >= N_NODES) arow = N_NODES - 1;
  const float* xrow = x + (size_t)arow * IN_F + ((lane >> 4) & 3) * 8;

  f32x4 acc0 = {0.f, 0.f, 0.f, 0.f};
  f32x4 acc1 = {0.f, 0.f, 0.f, 0.f};
  f32x4 acc2 = {0.f, 0.f, 0.f, 0.f};
  f32x4 acc3 = {0.f, 0.f, 0.f, 0.f};

#pragma unroll
  for (int s = 0; s < 8; ++s) {
    const float4 f0 = *reinterpret_cast<const float4*>(xrow + s * 32);
    const float4 f1 = *reinterpret_cast<const float4*>(xrow + s * 32 + 4);
    bf16x8 a;
    a[0] = f2bf(f0.x); a[1] = f2bf(f0.y); a[2] = f2bf(f0.z); a[3] = f2bf(f0.w);
    a[4] = f2bf(f1.x); a[5] = f2bf(f1.y); a[6] = f2bf(f1.z); a[7] = f2bf(f1.w);
    const bf16x8 b0 = *reinterpret_cast<const bf16x8*>(&sWf[((s * 4 + 0) * 64 + lane) * 8]);
    const bf16x8 b1 = *reinterpret_cast<const bf16x8*>(&sWf[((s * 4 + 1) * 64 + lane) * 8]);
    const bf16x8 b2 = *reinterpret_cast<const bf16x8*>(&sWf[((s * 4 + 2) * 64 + lane) * 8]);
    const bf16x8 b3 = *reinterpret_cast<const bf16x8*>(&sWf[((s * 4 + 3) * 64 + lane) * 8]);
    acc0 = __builtin_amdgcn_mfma_f32_16x16x32_bf16(a, b0, acc0, 0, 0, 0);
    acc1 = __builtin_amdgcn_mfma_f32_16x16x32_bf16(a, b1, acc1, 0, 0, 0);
    acc2 = __builtin_amdgcn_mfma_f32_16x16x32_bf16(a, b2, acc2, 0, 0, 0);
    acc3 = __builtin_amdgcn_mfma_f32_16x16x32_bf16(a, b3, acc3, 0, 0, 0);
  }

  const int orow_base = r0_base + ((lane >> 4) & 3) * 4;
  const int ocol = lane & 15;
#pragma unroll
  for (int r = 0; r < 4; ++r) {
    const int row = orow_base + r;
    if (row < N_NODES) {
      unsigned short* o = supB + (size_t)row * OUT_F + ocol;
      o[0]  = (unsigned short)f2bf(acc0[r]);
      o[16] = (unsigned short)f2bf(acc1[r]);
      o[32] = (unsigned short)f2bf(acc2[r]);
      o[48] = (unsigned short)f2bf(acc3[r]);
    }
  }
}

// ---------------------------------------------------------------------------
// Kernel 3: out[n] = bias + sum_{e in row n} ev[e] * supB[col[e]]
// TWO nodes per wave iteration: pair (nA, nA+1), 4 independent u16x8 gather
// loads (32 edges) in flight per latency window -> ~6 windows per wave
// instead of ~12. lane -> (g = lane>>3 edge subgroup, fo = lane&7 feature
// octet). Reduce = 3 shfl_xor per acc; lanes 0-7 store 32 B per node.
// N_NODES even and nA always even => pair always valid. Deterministic.
// ---------------------------------------------------------------------------
__global__ __launch_bounds__(256) void spmm_kernel(
    const unsigned short* __restrict__ supB, const float* __restrict__ ev,
    const int* __restrict__ col, const int* __restrict__ row_ptr,
    const float* __restrict__ bias, float* __restrict__ out) {
  const int lane = threadIdx.x & 63;
  const int g = lane >> 3;   // edge subgroup 0..7
  const int fo = lane & 7;   // feature octet 0..7
  const int gwave = (blockIdx.x * blockDim.x + threadIdx.x) >> 6;
  const int nwaves = (gridDim.x * blockDim.x) >> 6;

  float b[8];
#pragma unroll
  for (int j = 0; j < 8; ++j) b[j] = bias[fo * 8 + j];

  for (int nA = gwave * 2; nA < N_NODES; nA += nwaves * 2) {
    const int sA = row_ptr[nA];
    const int eA = row_ptr[nA + 1];
    const int eB = row_ptr[nA + 2];  // nA even, N_NODES even -> nA+1 valid

    float accA[8] = {0.f, 0.f, 0.f, 0.f, 0.f, 0.f, 0.f, 0.f};
    float accB[8] = {0.f, 0.f, 0.f, 0.f, 0.f, 0.f, 0.f, 0.f};

    int iA = sA, iB = eA;
    while (iA < eA || iB < eB) {
      const int a0i = iA + g,     a1i = iA + 8 + g;
      const int b0i = iB + g,     b1i = iB + 8 + g;
      const bool pa0 = a0i < eA,  pa1 = a1i < eA;
      const bool pb0 = b0i < eB,  pb1 = b1i < eB;

      const int ca0 = col[pa0 ? a0i : sA];
      const int ca1 = col[pa1 ? a1i : sA];
      const int cb0 = col[pb0 ? b0i : sA];
      const int cb1 = col[pb1 ? b1i : sA];
      const float va0 = pa0 ? ev[a0i] : 0.f;
      const float va1 = pa1 ? ev[a1i] : 0.f;
      const float vb0 = pb0 ? ev[b0i] : 0.f;
      const float vb1 = pb1 ? ev[b1i] : 0.f;

      const u16x8 sa0 = *reinterpret_cast<const u16x8*>(supB + (size_t)ca0 * OUT_F + fo * 8);
      const u16x8 sa1 = *reinterpret_cast<const u16x8*>(supB + (size_t)ca1 * OUT_F + fo * 8);
      const u16x8 sb0 = *reinterpret_cast<const u16x8*>(supB + (size_t)cb0 * OUT_F + fo * 8);
      const u16x8 sb1 = *reinterpret_cast<const u16x8*>(supB + (size_t)cb1 * OUT_F + fo * 8);

#pragma unroll
      for (int j = 0; j < 8; ++j) accA[j] = fmaf(va0, bf2f(sa0[j]), accA[j]);
#pragma unroll
      for (int j = 0; j < 8; ++j) accA[j] = fmaf(va1, bf2f(sa1[j]), accA[j]);
#pragma unroll
      for (int j = 0; j < 8; ++j) accB[j] = fmaf(vb0, bf2f(sb0[j]), accB[j]);
#pragma unroll
      for (int j = 0; j < 8; ++j) accB[j] = fmaf(vb1, bf2f(sb1[j]), accB[j]);

      iA += 16; iB += 16;
    }

    // reduce across the 8 edge subgroups (lane bits 3,4,5)
#pragma unroll
    for (int j = 0; j < 8; ++j) {
      accA[j] += __shfl_xor(accA[j], 8);
      accA[j] += __shfl_xor(accA[j], 16);
      accA[j] += __shfl_xor(accA[j], 32);
      accB[j] += __shfl_xor(accB[j], 8);
      accB[j] += __shfl_xor(accB[j], 16);
      accB[j] += __shfl_xor(accB[j], 32);
    }

    if (lane < 8) {
      float* oA = out + (size_t)nA * OUT_F + fo * 8;
      float* oB = out + (size_t)(nA + 1) * OUT_F + fo * 8;
      f32x4 a0 = {accA[0] + b[0], accA[1] + b[1], accA[2] + b[2], accA[3] + b[3]};
      f32x4 a1 = {accA[4] + b[4], accA[5] + b[5], accA[6] + b[6], accA[7] + b[7]};
      f32x4 b0 = {accB[0] + b[0], accB[1] + b[1], accB[2] + b[2], accB[3] + b[3]};
      f32x4 b1 = {accB[4] + b[4], accB[5] + b[5], accB[6] + b[6], accB[7] + b[7]};
      *reinterpret_cast<f32x4*>(oA) = a0;
      *reinterpret_cast<f32x4*>(oA + 4) = a1;
      *reinterpret_cast<f32x4*>(oB) = b0;
      *reinterpret_cast<f32x4*>(oB + 4) = b1;
    }
  }
}

extern "C" void kernel_launch(void* const* d_in, const int* in_sizes, int n_in,
                              void* d_out, int out_size, void* d_ws, size_t ws_size,
                              hipStream_t stream) {
  const float* x        = (const float*)d_in[0];
  const float* ev       = (const float*)d_in[1];
  const float* W        = (const float*)d_in[2];
  const float* bias     = (const float*)d_in[3];
  const int*   row_idx  = (const int*)d_in[4];
  const int*   col_idx  = (const int*)d_in[5];
  float* out = (float*)d_out;

  // Workspace: [0, 400KB) row_ptr; [448KB, 480KB) W-fragments (bf16);
  //            [512KB, +12.8MB) support bf16.
  int*            row_ptr = (int*)d_ws;
  short*          Wf      = (short*)((char*)d_ws + 448 * 1024);
  unsigned short* supB    = (unsigned short*)((char*)d_ws + 512 * 1024);

  build_row_ptr_kernel<<<(N_NODES + 1 + 255) / 256, 256, 0, stream>>>(row_idx, row_ptr);
  wfrag_kernel<<<8, 256, 0, stream>>>(W, Wf);

  gemm_kernel<<<(N_NODES + 63) / 64, 256, 0, stream>>>(x, Wf, supB);

  spmm_kernel<<<2048, 256, 0, stream>>>(supB, ev, col_idx, row_ptr, bias, out);
}

// Round 7
// 70.204 us; speedup vs baseline: 1.0891x; 1.0891x over previous
//
#include <hip/hip_runtime.h>
#include <hip/hip_bf16.h>

#define N_NODES 100000
#define N_EDGES 1600000
#define IN_F 256
#define OUT_F 64

typedef short bf16x8 __attribute__((ext_vector_type(8)));
typedef float f32x4 __attribute__((ext_vector_type(4)));
typedef unsigned short u16x8 __attribute__((ext_vector_type(8)));

__device__ __forceinline__ short f2bf(float f) {
  unsigned u = __float_as_uint(f);
  u += 0x7FFF + ((u >> 16) & 1);  // round-to-nearest-even
  return (short)(u >> 16);
}
__device__ __forceinline__ float bf2f(unsigned short u) {
  return __uint_as_float(((unsigned)u) << 16);
}

// ---------------------------------------------------------------------------
// Kernel 1 (fused prep): blocks [0,391] build CSR row pointers (binary
// search over sorted row_idx); blocks [392,399] build bf16 W-fragments.
//   Wf: k = s*32 + (l>>4)*8 + j, col = t*16 + (l&15)
// ---------------------------------------------------------------------------
__global__ __launch_bounds__(256) void prep_kernel(
    const int* __restrict__ row_idx, int* __restrict__ row_ptr,
    const float* __restrict__ W, short* __restrict__ Wf) {
  const int b = blockIdx.x;
  if (b < 392) {
    int i = b * 256 + threadIdx.x;
    if (i > N_NODES) return;
    int lo = 0, hi = N_EDGES;
    while (lo < hi) {
      int mid = (lo + hi) >> 1;
      if (row_idx[mid] < i) lo = mid + 1; else hi = mid;
    }
    row_ptr[i] = lo;
  } else {
    int tid = (b - 392) * 256 + threadIdx.x;  // [0, 2048)
    int s = tid >> 8;
    int r = tid & 255;
    int t = r >> 6;
    int lane = r & 63;
    int col = t * 16 + (lane & 15);
    int kbase = s * 32 + ((lane >> 4) & 3) * 8;
#pragma unroll
    for (int j = 0; j < 8; ++j) {
      Wf[(size_t)tid * 8 + j] = f2bf(W[(size_t)(kbase + j) * OUT_F + col]);
    }
  }
}

// ---------------------------------------------------------------------------
// Kernel 2: support(bf16) = x @ W via bf16 MFMA (16x16x32). (unchanged)
// C/D layout (HW-verified): col = lane&15, row = (lane>>4)*4 + reg.
// ---------------------------------------------------------------------------
__global__ __launch_bounds__(256) void gemm_kernel(
    const float* __restrict__ x, const short* __restrict__ Wf,
    unsigned short* __restrict__ supB) {
  __shared__ short sWf[8 * 4 * 64 * 8];  // 32 KB
  {
    const float4* g = reinterpret_cast<const float4*>(Wf);
    float4* s4 = reinterpret_cast<float4*>(sWf);
#pragma unroll
    for (int i = 0; i < 8; ++i) s4[threadIdx.x + i * 256] = g[threadIdx.x + i * 256];
  }
  __syncthreads();

  const int lane = threadIdx.x & 63;
  const int wave = threadIdx.x >> 6;
  const int r0_base = blockIdx.x * 64 + wave * 16;

  int arow = r0_base + (lane & 15);
  if (arow >= N_NODES) arow = N_NODES - 1;
  const float* xrow = x + (size_t)arow * IN_F + ((lane >> 4) & 3) * 8;

  f32x4 acc0 = {0.f, 0.f, 0.f, 0.f};
  f32x4 acc1 = {0.f, 0.f, 0.f, 0.f};
  f32x4 acc2 = {0.f, 0.f, 0.f, 0.f};
  f32x4 acc3 = {0.f, 0.f, 0.f, 0.f};

#pragma unroll
  for (int s = 0; s < 8; ++s) {
    const float4 f0 = *reinterpret_cast<const float4*>(xrow + s * 32);
    const float4 f1 = *reinterpret_cast<const float4*>(xrow + s * 32 + 4);
    bf16x8 a;
    a[0] = f2bf(f0.x); a[1] = f2bf(f0.y); a[2] = f2bf(f0.z); a[3] = f2bf(f0.w);
    a[4] = f2bf(f1.x); a[5] = f2bf(f1.y); a[6] = f2bf(f1.z); a[7] = f2bf(f1.w);
    const bf16x8 b0 = *reinterpret_cast<const bf16x8*>(&sWf[((s * 4 + 0) * 64 + lane) * 8]);
    const bf16x8 b1 = *reinterpret_cast<const bf16x8*>(&sWf[((s * 4 + 1) * 64 + lane) * 8]);
    const bf16x8 b2 = *reinterpret_cast<const bf16x8*>(&sWf[((s * 4 + 2) * 64 + lane) * 8]);
    const bf16x8 b3 = *reinterpret_cast<const bf16x8*>(&sWf[((s * 4 + 3) * 64 + lane) * 8]);
    acc0 = __builtin_amdgcn_mfma_f32_16x16x32_bf16(a, b0, acc0, 0, 0, 0);
    acc1 = __builtin_amdgcn_mfma_f32_16x16x32_bf16(a, b1, acc1, 0, 0, 0);
    acc2 = __builtin_amdgcn_mfma_f32_16x16x32_bf16(a, b2, acc2, 0, 0, 0);
    acc3 = __builtin_amdgcn_mfma_f32_16x16x32_bf16(a, b3, acc3, 0, 0, 0);
  }

  const int orow_base = r0_base + ((lane >> 4) & 3) * 4;
  const int ocol = lane & 15;
#pragma unroll
  for (int r = 0; r < 4; ++r) {
    const int row = orow_base + r;
    if (row < N_NODES) {
      unsigned short* o = supB + (size_t)row * OUT_F + ocol;
      o[0]  = (unsigned short)f2bf(acc0[r]);
      o[16] = (unsigned short)f2bf(acc1[r]);
      o[32] = (unsigned short)f2bf(acc2[r]);
      o[48] = (unsigned short)f2bf(acc3[r]);
    }
  }
}

// ---------------------------------------------------------------------------
// Kernel 3: out[n] = bias + sum_{e in row n} ev[e] * supB[col[e]]
// Software-pipelined: contiguous node range per wave -> col/ev is one
// forward stream. Next window's col/ev prefetched (unpredicated, clamped)
// while current window's gathers are in flight; predicates applied on ev at
// consume time only, so gathers start straight from registers. row_ptr[n+2]
// prefetched at each node advance. Window = 16 edges (2 u16x8 gathers,
// lane -> g=lane>>3 edge subgroup, fo=lane&7 feature octet).
// Reduce = 3 shfl_xor; lanes 0-7 store 32 B. Deterministic, no atomics.
// ---------------------------------------------------------------------------
__global__ __launch_bounds__(256) void spmm_kernel(
    const unsigned short* __restrict__ supB, const float* __restrict__ ev,
    const int* __restrict__ col, const int* __restrict__ row_ptr,
    const float* __restrict__ bias, float* __restrict__ out) {
  const int lane = threadIdx.x & 63;
  const int g = lane >> 3;   // edge subgroup 0..7
  const int fo = lane & 7;   // feature octet 0..7
  const int gwave = (blockIdx.x * blockDim.x + threadIdx.x) >> 6;
  const int nwaves = (gridDim.x * blockDim.x) >> 6;  // 8192

  const int per = (N_NODES + nwaves - 1) / nwaves;
  const int n0 = gwave * per;
  if (n0 >= N_NODES) return;
  const int n1 = (n0 + per < N_NODES) ? n0 + per : N_NODES;

  float b[8];
#pragma unroll
  for (int j = 0; j < 8; ++j) b[j] = bias[fo * 8 + j];

  int n = n0;
  int i = row_ptr[n0];
  int eCur = row_ptr[n0 + 1];
  int eNext = row_ptr[(n0 + 2 <= N_NODES) ? n0 + 2 : N_NODES];

  // preload window 0 stream
  int pos0 = i + g, pos1 = i + 8 + g;
  int cp0 = pos0 < N_EDGES ? pos0 : N_EDGES - 1;
  int cp1 = pos1 < N_EDGES ? pos1 : N_EDGES - 1;
  int   c0 = col[cp0];
  int   c1 = col[cp1];
  float v0 = ev[cp0];
  float v1 = ev[cp1];

  float acc[8] = {0.f, 0.f, 0.f, 0.f, 0.f, 0.f, 0.f, 0.f};

  while (true) {
    const bool more = (i + 16 < eCur);      // wave-uniform
    const int ni = more ? (i + 16) : eCur;  // next window start

    // prefetch next window's stream (unpredicated, clamped)
    const int np0 = ni + g, np1 = ni + 8 + g;
    const int ncp0 = np0 < N_EDGES ? np0 : N_EDGES - 1;
    const int ncp1 = np1 < N_EDGES ? np1 : N_EDGES - 1;
    const int   nc0 = col[ncp0];
    const int   nc1 = col[ncp1];
    const float nv0 = ev[ncp0];
    const float nv1 = ev[ncp1];

    // consume current window: gather addresses ready in registers
    const float u0 = (pos0 < eCur) ? v0 : 0.f;
    const float u1 = (pos1 < eCur) ? v1 : 0.f;
    const u16x8 s0 = *reinterpret_cast<const u16x8*>(supB + (size_t)c0 * OUT_F + fo * 8);
    const u16x8 s1 = *reinterpret_cast<const u16x8*>(supB + (size_t)c1 * OUT_F + fo * 8);
#pragma unroll
    for (int j = 0; j < 8; ++j) acc[j] = fmaf(u0, bf2f(s0[j]), acc[j]);
#pragma unroll
    for (int j = 0; j < 8; ++j) acc[j] = fmaf(u1, bf2f(s1[j]), acc[j]);

    if (!more) {
      // finalize node n (wave-uniform branch)
#pragma unroll
      for (int j = 0; j < 8; ++j) {
        acc[j] += __shfl_xor(acc[j], 8);
        acc[j] += __shfl_xor(acc[j], 16);
        acc[j] += __shfl_xor(acc[j], 32);
      }
      if (lane < 8) {
        float* o = out + (size_t)n * OUT_F + fo * 8;
        f32x4 oA = {acc[0] + b[0], acc[1] + b[1], acc[2] + b[2], acc[3] + b[3]};
        f32x4 oB = {acc[4] + b[4], acc[5] + b[5], acc[6] + b[6], acc[7] + b[7]};
        *reinterpret_cast<f32x4*>(o) = oA;
        *reinterpret_cast<f32x4*>(o + 4) = oB;
      }
      ++n;
      if (n >= n1) break;
#pragma unroll
      for (int j = 0; j < 8; ++j) acc[j] = 0.f;
      eCur = eNext;
      eNext = row_ptr[(n + 2 <= N_NODES) ? n + 2 : N_NODES];
    }

    i = ni;
    pos0 = np0; pos1 = np1;
    c0 = nc0; c1 = nc1;
    v0 = nv0; v1 = nv1;
  }
}

extern "C" void kernel_launch(void* const* d_in, const int* in_sizes, int n_in,
                              void* d_out, int out_size, void* d_ws, size_t ws_size,
                              hipStream_t stream) {
  const float* x        = (const float*)d_in[0];
  const float* ev       = (const float*)d_in[1];
  const float* W        = (const float*)d_in[2];
  const float* bias     = (const float*)d_in[3];
  const int*   row_idx  = (const int*)d_in[4];
  const int*   col_idx  = (const int*)d_in[5];
  float* out = (float*)d_out;

  // Workspace: [0, 400KB) row_ptr; [448KB, 480KB) W-fragments (bf16);
  //            [512KB, +12.8MB) support bf16.
  int*            row_ptr = (int*)d_ws;
  short*          Wf      = (short*)((char*)d_ws + 448 * 1024);
  unsigned short* supB    = (unsigned short*)((char*)d_ws + 512 * 1024);

  // Fused prep: 392 row_ptr blocks + 8 wfrag blocks.
  prep_kernel<<<400, 256, 0, stream>>>(row_idx, row_ptr, W, Wf);

  gemm_kernel<<<(N_NODES + 63) / 64, 256, 0, stream>>>(x, Wf, supB);

  spmm_kernel<<<2048, 256, 0, stream>>>(supB, ev, col_idx, row_ptr, bias, out);
}

// Round 8
// 68.979 us; speedup vs baseline: 1.1084x; 1.0178x over previous
//
#include <hip/hip_runtime.h>
#include <hip/hip_bf16.h>
#include <hip/hip_fp16.h>

#define N_NODES 100000
#define N_EDGES 1600000
#define IN_F 256
#define OUT_F 64

typedef short bf16x8 __attribute__((ext_vector_type(8)));
typedef float f32x4 __attribute__((ext_vector_type(4)));
typedef _Float16 half8 __attribute__((ext_vector_type(8)));

__device__ __forceinline__ short f2bf(float f) {
  unsigned u = __float_as_uint(f);
  u += 0x7FFF + ((u >> 16) & 1);  // round-to-nearest-even
  return (short)(u >> 16);
}

// ---------------------------------------------------------------------------
// Kernel 1 (fused prep): blocks [0,391] build CSR row pointers (binary
// search over sorted row_idx); blocks [392,399] build bf16 W-fragments.
//   Wf: k = s*32 + (l>>4)*8 + j, col = t*16 + (l&15)
// ---------------------------------------------------------------------------
__global__ __launch_bounds__(256) void prep_kernel(
    const int* __restrict__ row_idx, int* __restrict__ row_ptr,
    const float* __restrict__ W, short* __restrict__ Wf) {
  const int b = blockIdx.x;
  if (b < 392) {
    int i = b * 256 + threadIdx.x;
    if (i > N_NODES) return;
    int lo = 0, hi = N_EDGES;
    while (lo < hi) {
      int mid = (lo + hi) >> 1;
      if (row_idx[mid] < i) lo = mid + 1; else hi = mid;
    }
    row_ptr[i] = lo;
  } else {
    int tid = (b - 392) * 256 + threadIdx.x;  // [0, 2048)
    int s = tid >> 8;
    int r = tid & 255;
    int t = r >> 6;
    int lane = r & 63;
    int col = t * 16 + (lane & 15);
    int kbase = s * 32 + ((lane >> 4) & 3) * 8;
#pragma unroll
    for (int j = 0; j < 8; ++j) {
      Wf[(size_t)tid * 8 + j] = f2bf(W[(size_t)(kbase + j) * OUT_F + col]);
    }
  }
}

// ---------------------------------------------------------------------------
// Kernel 2: support(fp16) = x @ W via bf16 MFMA (16x16x32).
// Epilogue stores fp16 (better mantissa than bf16; |support| << 65504).
// C/D layout (HW-verified): col = lane&15, row = (lane>>4)*4 + reg.
// ---------------------------------------------------------------------------
__global__ __launch_bounds__(256) void gemm_kernel(
    const float* __restrict__ x, const short* __restrict__ Wf,
    _Float16* __restrict__ supH) {
  __shared__ short sWf[8 * 4 * 64 * 8];  // 32 KB
  {
    const float4* g = reinterpret_cast<const float4*>(Wf);
    float4* s4 = reinterpret_cast<float4*>(sWf);
#pragma unroll
    for (int i = 0; i < 8; ++i) s4[threadIdx.x + i * 256] = g[threadIdx.x + i * 256];
  }
  __syncthreads();

  const int lane = threadIdx.x & 63;
  const int wave = threadIdx.x >> 6;
  const int r0_base = blockIdx.x * 64 + wave * 16;

  int arow = r0_base + (lane & 15);
  if (arow >= N_NODES) arow = N_NODES - 1;
  const float* xrow = x + (size_t)arow * IN_F + ((lane >> 4) & 3) * 8;

  f32x4 acc0 = {0.f, 0.f, 0.f, 0.f};
  f32x4 acc1 = {0.f, 0.f, 0.f, 0.f};
  f32x4 acc2 = {0.f, 0.f, 0.f, 0.f};
  f32x4 acc3 = {0.f, 0.f, 0.f, 0.f};

#pragma unroll
  for (int s = 0; s < 8; ++s) {
    const float4 f0 = *reinterpret_cast<const float4*>(xrow + s * 32);
    const float4 f1 = *reinterpret_cast<const float4*>(xrow + s * 32 + 4);
    bf16x8 a;
    a[0] = f2bf(f0.x); a[1] = f2bf(f0.y); a[2] = f2bf(f0.z); a[3] = f2bf(f0.w);
    a[4] = f2bf(f1.x); a[5] = f2bf(f1.y); a[6] = f2bf(f1.z); a[7] = f2bf(f1.w);
    const bf16x8 b0 = *reinterpret_cast<const bf16x8*>(&sWf[((s * 4 + 0) * 64 + lane) * 8]);
    const bf16x8 b1 = *reinterpret_cast<const bf16x8*>(&sWf[((s * 4 + 1) * 64 + lane) * 8]);
    const bf16x8 b2 = *reinterpret_cast<const bf16x8*>(&sWf[((s * 4 + 2) * 64 + lane) * 8]);
    const bf16x8 b3 = *reinterpret_cast<const bf16x8*>(&sWf[((s * 4 + 3) * 64 + lane) * 8]);
    acc0 = __builtin_amdgcn_mfma_f32_16x16x32_bf16(a, b0, acc0, 0, 0, 0);
    acc1 = __builtin_amdgcn_mfma_f32_16x16x32_bf16(a, b1, acc1, 0, 0, 0);
    acc2 = __builtin_amdgcn_mfma_f32_16x16x32_bf16(a, b2, acc2, 0, 0, 0);
    acc3 = __builtin_amdgcn_mfma_f32_16x16x32_bf16(a, b3, acc3, 0, 0, 0);
  }

  const int orow_base = r0_base + ((lane >> 4) & 3) * 4;
  const int ocol = lane & 15;
#pragma unroll
  for (int r = 0; r < 4; ++r) {
    const int row = orow_base + r;
    if (row < N_NODES) {
      _Float16* o = supH + (size_t)row * OUT_F + ocol;
      o[0]  = (_Float16)acc0[r];
      o[16] = (_Float16)acc1[r];
      o[32] = (_Float16)acc2[r];
      o[48] = (_Float16)acc3[r];
    }
  }
}

// ---------------------------------------------------------------------------
// Kernel 3: out[n] = bias + sum_{e in row n} ev[e] * supH[col[e]]
// Edge-quantile balanced: wave w owns nodes [n_w, n_{w+1}) where
// n_w = row_idx[w*E/W - 1] + 1 (exact partition, ~195 edges/wave).
// Software-pipelined stream (r7); fp16 gather rows consumed via
// fmaf(ev, (float)h, acc) -> v_fma_mix / cvt, no manual unpack.
// Window = 16 edges (2 half8 gathers; g=lane>>3 edge subgroup, fo=lane&7
// feature octet). Reduce = 3 shfl_xor; lanes 0-7 store 32 B. Deterministic.
// ---------------------------------------------------------------------------
__global__ __launch_bounds__(256) void spmm_kernel(
    const _Float16* __restrict__ supH, const float* __restrict__ ev,
    const int* __restrict__ col, const int* __restrict__ row_ptr,
    const int* __restrict__ row_idx,
    const float* __restrict__ bias, float* __restrict__ out) {
  const int lane = threadIdx.x & 63;
  const int g = lane >> 3;   // edge subgroup 0..7
  const int fo = lane & 7;   // feature octet 0..7
  const int gwave = (blockIdx.x * blockDim.x + threadIdx.x) >> 6;
  const int nwaves = (gridDim.x * blockDim.x) >> 6;  // 8192

  // exact edge-quantile node range
  const long k0 = ((long)gwave * N_EDGES) / nwaves;
  const long k1 = ((long)(gwave + 1) * N_EDGES) / nwaves;
  const int n0 = (k0 == 0) ? 0 : (row_idx[k0 - 1] + 1);
  const int n1 = (gwave + 1 >= nwaves) ? N_NODES : (row_idx[k1 - 1] + 1);
  if (n0 >= n1) return;

  float b[8];
#pragma unroll
  for (int j = 0; j < 8; ++j) b[j] = bias[fo * 8 + j];

  int n = n0;
  int i = row_ptr[n0];
  int eCur = row_ptr[n0 + 1];
  int eNext = row_ptr[(n0 + 2 <= N_NODES) ? n0 + 2 : N_NODES];

  // preload window 0 stream
  int pos0 = i + g, pos1 = i + 8 + g;
  int cp0 = pos0 < N_EDGES ? pos0 : N_EDGES - 1;
  int cp1 = pos1 < N_EDGES ? pos1 : N_EDGES - 1;
  int   c0 = col[cp0];
  int   c1 = col[cp1];
  float v0 = ev[cp0];
  float v1 = ev[cp1];

  float acc[8] = {0.f, 0.f, 0.f, 0.f, 0.f, 0.f, 0.f, 0.f};

  while (true) {
    const bool more = (i + 16 < eCur);      // wave-uniform
    const int ni = more ? (i + 16) : eCur;  // next window start

    // prefetch next window's stream (unpredicated, clamped)
    const int np0 = ni + g, np1 = ni + 8 + g;
    const int ncp0 = np0 < N_EDGES ? np0 : N_EDGES - 1;
    const int ncp1 = np1 < N_EDGES ? np1 : N_EDGES - 1;
    const int   nc0 = col[ncp0];
    const int   nc1 = col[ncp1];
    const float nv0 = ev[ncp0];
    const float nv1 = ev[ncp1];

    // consume current window: gather addresses ready in registers
    const float u0 = (pos0 < eCur) ? v0 : 0.f;
    const float u1 = (pos1 < eCur) ? v1 : 0.f;
    const half8 s0 = *reinterpret_cast<const half8*>(
        supH + (unsigned)((c0 << 6) + fo * 8));
    const half8 s1 = *reinterpret_cast<const half8*>(
        supH + (unsigned)((c1 << 6) + fo * 8));
#pragma unroll
    for (int j = 0; j < 8; ++j) acc[j] = fmaf(u0, (float)s0[j], acc[j]);
#pragma unroll
    for (int j = 0; j < 8; ++j) acc[j] = fmaf(u1, (float)s1[j], acc[j]);

    if (!more) {
      // finalize node n (wave-uniform branch)
#pragma unroll
      for (int j = 0; j < 8; ++j) {
        acc[j] += __shfl_xor(acc[j], 8);
        acc[j] += __shfl_xor(acc[j], 16);
        acc[j] += __shfl_xor(acc[j], 32);
      }
      if (lane < 8) {
        float* o = out + (size_t)n * OUT_F + fo * 8;
        f32x4 oA = {acc[0] + b[0], acc[1] + b[1], acc[2] + b[2], acc[3] + b[3]};
        f32x4 oB = {acc[4] + b[4], acc[5] + b[5], acc[6] + b[6], acc[7] + b[7]};
        *reinterpret_cast<f32x4*>(o) = oA;
        *reinterpret_cast<f32x4*>(o + 4) = oB;
      }
      ++n;
      if (n >= n1) break;
#pragma unroll
      for (int j = 0; j < 8; ++j) acc[j] = 0.f;
      eCur = eNext;
      eNext = row_ptr[(n + 2 <= N_NODES) ? n + 2 : N_NODES];
    }

    i = ni;
    pos0 = np0; pos1 = np1;
    c0 = nc0; c1 = nc1;
    v0 = nv0; v1 = nv1;
  }
}

extern "C" void kernel_launch(void* const* d_in, const int* in_sizes, int n_in,
                              void* d_out, int out_size, void* d_ws, size_t ws_size,
                              hipStream_t stream) {
  const float* x        = (const float*)d_in[0];
  const float* ev       = (const float*)d_in[1];
  const float* W        = (const float*)d_in[2];
  const float* bias     = (const float*)d_in[3];
  const int*   row_idx  = (const int*)d_in[4];
  const int*   col_idx  = (const int*)d_in[5];
  float* out = (float*)d_out;

  // Workspace: [0, 400KB) row_ptr; [448KB, 480KB) W-fragments (bf16);
  //            [512KB, +12.8MB) support fp16.
  int*       row_ptr = (int*)d_ws;
  short*     Wf      = (short*)((char*)d_ws + 448 * 1024);
  _Float16*  supH    = (_Float16*)((char*)d_ws + 512 * 1024);

  // Fused prep: 392 row_ptr blocks + 8 wfrag blocks.
  prep_kernel<<<400, 256, 0, stream>>>(row_idx, row_ptr, W, Wf);

  gemm_kernel<<<(N_NODES + 63) / 64, 256, 0, stream>>>(x, Wf, supH);

  spmm_kernel<<<2048, 256, 0, stream>>>(supH, ev, col_idx, row_ptr, row_idx, bias, out);
}